// Round 6
// baseline (6771.626 us; speedup 1.0000x reference)
//
#include <hip/hip_runtime.h>
#include <cmath>

// ---------------------------------------------------------------------------
// Round 6 = Round 5 with 2 blocks/CU for barrier-latency hiding:
// 512 blocks x 512 threads x 2 rows/block (was 256 x 4 rows, 1 block/CU ->
// every __syncthreads stalled the whole CU; occupancy 23.7%, 6.95K cyc/step
// vs ~3.5K work). Weight B-frags per-wave (VGPR unchanged 112 <= 128 cap via
// __launch_bounds__(512,4)); LDS ~39KB/block -> 2 blocks fit.
// Structure per block unchanged: register-resident MFMA weights, 4 barriers/
// step, lane-linear conflict-free A-frags, R1 in P1 / R2 in P2.
// ---------------------------------------------------------------------------

typedef _Float16 half8 __attribute__((ext_vector_type(8)));
typedef float floatx4 __attribute__((ext_vector_type(4)));

// ws layout: f16 region (offsets in _Float16 units)
#define H_FW1 0        // [128][64]
#define H_GW1 8192     // [128][64]
#define H_FW2 16384    // [128][128]
#define H_GW2 32768    // [128][128]
#define H_FW3 49152    // [64][128]
#define H_GW3 57344    // [512][128]
#define H_RW1 122880   // [128][64]
#define H_TOTAL 131072
// f32 region (offsets in float units from ws base)
#define F_BASE 65536
#define F_RW2T (F_BASE + 0)      // [16][132]
#define F_EMBT (F_BASE + 2112)   // [64][32]
#define F_W1R0F (F_BASE + 4160)  // [128]
#define F_W1R0G (F_BASE + 4288)  // [128]
#define F_CNT 4416
#define PREP_TOTAL (H_TOTAL + F_CNT)

__global__ void prep_kernel(const float* __restrict__ fW1, const float* __restrict__ gW1,
                            const float* __restrict__ fW2, const float* __restrict__ gW2,
                            const float* __restrict__ fW3, const float* __restrict__ gW3,
                            const float* __restrict__ rW1, const float* __restrict__ rW2,
                            const float* __restrict__ embW, void* __restrict__ ws) {
  int idx = blockIdx.x * blockDim.x + threadIdx.x;
  if (idx >= PREP_TOTAL) return;
  if (idx < H_TOTAL) {
    float v;
    if (idx < H_GW1) {
      int t = idx; int c = t >> 6, k = t & 63; v = fW1[(k + 1) * 128 + c];
    } else if (idx < H_FW2) {
      int t = idx - H_GW1; int c = t >> 6, k = t & 63; v = gW1[(k + 1) * 128 + c];
    } else if (idx < H_GW2) {
      int t = idx - H_FW2; int c = t >> 7, k = t & 127; v = fW2[k * 128 + c];
    } else if (idx < H_FW3) {
      int t = idx - H_GW2; int c = t >> 7, k = t & 127; v = gW2[k * 128 + c];
    } else if (idx < H_GW3) {
      int t = idx - H_FW3; int c = t >> 7, k = t & 127; v = fW3[k * 64 + c];
    } else if (idx < H_RW1) {
      int t = idx - H_GW3; int c = t >> 7, k = t & 127; v = gW3[k * 512 + c];
    } else {
      int t = idx - H_RW1; int c = t >> 6, k = t & 63; v = rW1[k * 128 + c];
    }
    ((_Float16*)ws)[idx] = (_Float16)v;
  } else {
    int f = idx - H_TOTAL;
    float v;
    if (f < 2112) {
      int c = f / 132, k = f % 132; v = (k < 128) ? rW2[k * 16 + c] : 0.f;
    } else if (f < 4160) {
      int t = f - 2112; int c = t >> 5, k = t & 31; v = embW[k * 64 + c];
    } else if (f < 4288) {
      v = fW1[f - 4160];     // fW1 row 0 (t-row)
    } else {
      v = gW1[f - 4288];     // gW1 row 0
    }
    ((float*)ws)[F_BASE + f] = v;
  }
}

__device__ __forceinline__ float sp(float x) { return __logf(1.f + __expf(x)); }

__device__ __forceinline__ float ftanh(float x) {
  float cx = fminf(fmaxf(x, -15.f), 15.f);
  float e = __expf(2.f * cx);
  return __fdividef(e - 1.f, e + 1.f);
}

__device__ __forceinline__ floatx4 mfma16(half8 a, half8 b, floatx4 c) {
  return __builtin_amdgcn_mfma_f32_16x16x32_f16(a, b, c, 0, 0, 0);
}

// lane-linear A-layout offset for element (m, k): seg(k>>5)*512 + ((k>>3)&3)*128 + m*8 + (k&7)
__device__ __forceinline__ int aofs(int m, int k) {
  return ((k >> 5) << 9) + (((k >> 3) & 3) << 7) + (m << 3) + (k & 7);
}

__global__ __launch_bounds__(512, 4)
void sde_main(const float* __restrict__ init_noise, const float* __restrict__ dw_noise,
              const float* __restrict__ emb_b,
              const float* __restrict__ f_b1, const float* __restrict__ f_b2,
              const float* __restrict__ f_b3, const float* __restrict__ g_b1,
              const float* __restrict__ g_b2, const float* __restrict__ g_b3,
              const float* __restrict__ r_b1, const float* __restrict__ r_b2,
              const void* __restrict__ ws, float* __restrict__ out_full,
              float* __restrict__ out_match) {
  // lane-linear f16 activation buffers (rows 2..15 hold garbage; never read)
  __shared__ __align__(16) _Float16 zseg[1024];                 // z, K=64 (2 segs)
  __shared__ __align__(16) _Float16 h1f[2048], h1g[2048];       // K=128 (4 segs)
  __shared__ __align__(16) _Float16 h2f[2048], h2g[2048];
  // f32 scratch (2 rows)
  __shared__ __align__(16) float hrs[2 * 132];    // readout hidden
  __shared__ __align__(16) float fps[2 * 68];     // f3 pre-act
  __shared__ __align__(16) float gps[2 * 528];    // g3 pre-act
  __shared__ __align__(16) float zb[2 * 68];      // z state f32
  __shared__ __align__(16) float dwS[2][12];
  __shared__ __align__(16) float rw2s[16 * 132];
  __shared__ float b1f[128], b1g[128], b2f[128], b2g[128], fb3[64], gb3[512];
  __shared__ float rb1[128], rb2[16], w1r0f[128], w1r0g[128];

  const int tid = threadIdx.x;
  const int w = tid >> 6;          // wave 0..7
  const int lane = tid & 63;
  const int ln16 = lane & 15;
  const int quad = lane >> 4;
  const int koff = quad * 8;
  const int wm = w & 3;
  const int b2 = blockIdx.x << 1;  // 2 rows per block
  const _Float16* wsh = (const _Float16*)ws;
  const float* wsf = (const float*)ws;

  const float DTI = 1.0f / 511.0f;
  const float SDT = sqrtf(DTI);

  // ---- init ----
  gb3[tid] = g_b3[tid];
  if (tid < 128) {
    b1f[tid] = f_b1[tid]; b1g[tid] = g_b1[tid];
    b2f[tid] = f_b2[tid]; b2g[tid] = g_b2[tid];
    rb1[tid] = r_b1[tid];
    w1r0f[tid] = wsf[F_W1R0F + tid]; w1r0g[tid] = wsf[F_W1R0G + tid];
  }
  if (tid < 64) fb3[tid] = f_b3[tid];
  if (tid < 16) rb2[tid] = r_b2[tid];
  for (int o = tid; o < 2112; o += 512) rw2s[o] = wsf[F_RW2T + o];
  if (tid < 64) hrs[(tid >> 5) * 132 + (tid & 31)] = init_noise[b2 * 32 + tid];

  // ---- persistent B-fragments (VGPR-resident for all 511 steps) ----
  half8 Bf1[2], Bg1[2], Br1[2], B2[2][4], B3g[4][4], B3f[4];
#pragma unroll
  for (int kf = 0; kf < 2; ++kf) {
    Bf1[kf] = *(const half8*)(wsh + H_FW1 + (w * 16 + ln16) * 64 + kf * 32 + koff);
    Bg1[kf] = *(const half8*)(wsh + H_GW1 + (w * 16 + ln16) * 64 + kf * 32 + koff);
    Br1[kf] = *(const half8*)(wsh + H_RW1 + (w * 16 + ln16) * 64 + kf * 32 + koff);
  }
  const _Float16* w2b = wsh + (w < 4 ? H_FW2 : H_GW2);
#pragma unroll
  for (int i2 = 0; i2 < 2; ++i2)
#pragma unroll
    for (int kf = 0; kf < 4; ++kf)
      B2[i2][kf] = *(const half8*)(w2b + ((wm * 2 + i2) * 16 + ln16) * 128 + kf * 32 + koff);
#pragma unroll
  for (int i2 = 0; i2 < 4; ++i2)
#pragma unroll
    for (int kf = 0; kf < 4; ++kf)
      B3g[i2][kf] = *(const half8*)(wsh + H_GW3 + ((w * 4 + i2) * 16 + ln16) * 128 + kf * 32 + koff);
  {  // fW3 tile w for waves 0-3 (cols w*16+ln16 < 64)
    int cw = (w < 4 ? w : 0);
#pragma unroll
    for (int kf = 0; kf < 4; ++kf)
      B3f[kf] = *(const half8*)(wsh + H_FW3 + (cw * 16 + ln16) * 128 + kf * 32 + koff);
  }
  __syncthreads();

  // ---- z0 = init_noise @ emb_W + emb_b ----
  if (tid < 128) {
    const int rr = tid & 1, l = tid >> 1;
    const float* pe = wsf + F_EMBT + l * 32;
    float acc = emb_b[l];
#pragma unroll
    for (int c = 0; c < 8; ++c) {
      float4 a = *(const float4*)(&hrs[rr * 132 + 4 * c]);
      float4 v = *(const float4*)(pe + 4 * c);
      acc += a.x * v.x + a.y * v.y + a.z * v.z + a.w * v.w;
    }
    zb[rr * 68 + l] = acc;
    zseg[aofs(rr, l)] = (_Float16)acc;
  }
  __syncthreads();

  // R2 helper: waves 4-7 (tid>=256), readout of hrs -> out[T]
  // t2 bits: r=bit0, kk=bits1-3 (8-way k-split), d=bits4-7
  auto R2 = [&](int T) {
    const int t2 = tid - 256;
    const int r = t2 & 1, q2 = t2 >> 1, d = q2 >> 3, kk = q2 & 7;
    const float* ph = &hrs[r * 132 + kk * 16];
    const float* pw = &rw2s[d * 132 + kk * 16];
    float acc = 0.f;
#pragma unroll
    for (int c = 0; c < 4; ++c) {
      float4 a4 = *(const float4*)(ph + 4 * c);
      float4 w4 = *(const float4*)(pw + 4 * c);
      acc += a4.x * w4.x + a4.y * w4.y + a4.z * w4.z + a4.w * w4.w;
    }
    acc += __shfl_xor(acc, 2);
    acc += __shfl_xor(acc, 4);
    acc += __shfl_xor(acc, 8);
    if (kk == 0) {
      float v = acc + rb2[d];
      out_full[((size_t)(b2 + r) * 512 + T) * 16 + d] = v;
      if ((T & 7) == 0) out_match[((size_t)(b2 + r) * 64 + (T >> 3)) * 16 + d] = v;
    }
  };

#pragma unroll 1
  for (int i = 0; i < 511; ++i) {
    const float t_s = (float)i * DTI;

    // ---- P1: L1 (f,g) + R1, all sharing z A-frags; dW prefetch (16 thr) ----
    {
      half8 a0 = *(const half8*)(&zseg[lane * 8]);
      half8 a1 = *(const half8*)(&zseg[512 + lane * 8]);
      floatx4 cf = {0.f, 0.f, 0.f, 0.f}, cg = {0.f, 0.f, 0.f, 0.f}, cr = {0.f, 0.f, 0.f, 0.f};
      cf = mfma16(a0, Bf1[0], cf); cf = mfma16(a1, Bf1[1], cf);
      cg = mfma16(a0, Bg1[0], cg); cg = mfma16(a1, Bg1[1], cg);
      cr = mfma16(a0, Br1[0], cr); cr = mfma16(a1, Br1[1], cr);
      if (tid >= 496) {
        int n = tid - 496;   // n = 0..15 (2 rows x 8 noise dims)
        dwS[n >> 3][n & 7] = dw_noise[(size_t)i * 8192 + b2 * 8 + n] * SDT;
      }
      if (quad == 0) {
        int col = w * 16 + ln16;
        float bf = b1f[col] + t_s * w1r0f[col];
        float bg = b1g[col] + t_s * w1r0g[col];
        int ho = aofs(0, col);   // +j*8 for row j
#pragma unroll
        for (int j = 0; j < 2; ++j) {
          h1f[ho + j * 8] = (_Float16)sp(cf[j] + bf);
          h1g[ho + j * 8] = (_Float16)sp(cg[j] + bg);
          hrs[j * 132 + col] = fmaxf(cr[j] + rb1[col], 0.f);
        }
      }
    }
    __syncthreads();

    // ---- P2: L2 (waves 0-3 f, 4-7 g) + R2(T=i) on waves 4-7 ----
    {
      const _Float16* asrc = (w < 4) ? h1f : h1g;
      half8 a[4];
#pragma unroll
      for (int s = 0; s < 4; ++s) a[s] = *(const half8*)(&asrc[s * 512 + lane * 8]);
      floatx4 c0 = {0.f, 0.f, 0.f, 0.f}, c1 = {0.f, 0.f, 0.f, 0.f};
#pragma unroll
      for (int s = 0; s < 4; ++s) {
        c0 = mfma16(a[s], B2[0][s], c0);
        c1 = mfma16(a[s], B2[1][s], c1);
      }
      if (tid >= 256) R2(i);
      if (quad == 0) {
        _Float16* dst = (w < 4) ? h2f : h2g;
        const float* bb = (w < 4) ? b2f : b2g;
        int col0 = wm * 32 + ln16, col1 = col0 + 16;
        int ho0 = aofs(0, col0), ho1 = aofs(0, col1);
#pragma unroll
        for (int j = 0; j < 2; ++j) {
          dst[ho0 + j * 8] = (_Float16)sp(c0[j] + bb[col0]);
          dst[ho1 + j * 8] = (_Float16)sp(c1[j] + bb[col1]);
        }
      }
    }
    __syncthreads();

    // ---- P3: L3 g (4 tiles/wave) + L3 f on waves 0-3 (reg B-frags) ----
    {
      half8 ag[4];
#pragma unroll
      for (int s = 0; s < 4; ++s) ag[s] = *(const half8*)(&h2g[s * 512 + lane * 8]);
      floatx4 cg4[4];
#pragma unroll
      for (int i2 = 0; i2 < 4; ++i2) cg4[i2] = (floatx4){0.f, 0.f, 0.f, 0.f};
#pragma unroll
      for (int s = 0; s < 4; ++s)
#pragma unroll
        for (int i2 = 0; i2 < 4; ++i2) cg4[i2] = mfma16(ag[s], B3g[i2][s], cg4[i2]);
      floatx4 cf3 = {0.f, 0.f, 0.f, 0.f};
      if (w < 4) {
#pragma unroll
        for (int s = 0; s < 4; ++s) {
          half8 af = *(const half8*)(&h2f[s * 512 + lane * 8]);
          cf3 = mfma16(af, B3f[s], cf3);
        }
      }
      if (quad == 0) {
#pragma unroll
        for (int i2 = 0; i2 < 4; ++i2) {
          int col = (w * 4 + i2) * 16 + ln16;
#pragma unroll
          for (int j = 0; j < 2; ++j) gps[j * 528 + col] = cg4[i2][j];
        }
        if (w < 4) {
          int col = w * 16 + ln16;
#pragma unroll
          for (int j = 0; j < 2; ++j) fps[j * 68 + col] = cf3[j];
        }
      }
    }
    __syncthreads();

    // ---- P4: z += tanh(f)*dt + sum tanh(g)*dW ; repack zseg ----
    if (tid < 128) {
      const int rr = tid & 1, l = tid >> 1;
      float acc = ftanh(fps[rr * 68 + l] + fb3[l]) * DTI;
      float4 g0 = *(const float4*)(&gps[rr * 528 + l * 8]);
      float4 g1 = *(const float4*)(&gps[rr * 528 + l * 8 + 4]);
      const float* gb = &gb3[l * 8];
      const float* dw = &dwS[rr][0];
      acc += ftanh(g0.x + gb[0]) * dw[0];
      acc += ftanh(g0.y + gb[1]) * dw[1];
      acc += ftanh(g0.z + gb[2]) * dw[2];
      acc += ftanh(g0.w + gb[3]) * dw[3];
      acc += ftanh(g1.x + gb[4]) * dw[4];
      acc += ftanh(g1.y + gb[5]) * dw[5];
      acc += ftanh(g1.z + gb[6]) * dw[6];
      acc += ftanh(g1.w + gb[7]) * dw[7];
      float zn = zb[rr * 68 + l] + acc;
      zb[rr * 68 + l] = zn;
      zseg[aofs(rr, l)] = (_Float16)zn;
    }
    __syncthreads();
  }

  // ---- final readout T=511 ----
  {
    half8 a0 = *(const half8*)(&zseg[lane * 8]);
    half8 a1 = *(const half8*)(&zseg[512 + lane * 8]);
    floatx4 cr = {0.f, 0.f, 0.f, 0.f};
    cr = mfma16(a0, Br1[0], cr); cr = mfma16(a1, Br1[1], cr);
    if (quad == 0) {
      int col = w * 16 + ln16;
#pragma unroll
      for (int j = 0; j < 2; ++j) hrs[j * 132 + col] = fmaxf(cr[j] + rb1[col], 0.f);
    }
  }
  __syncthreads();
  if (tid >= 256) R2(511);
}

extern "C" void kernel_launch(void* const* d_in, const int* in_sizes, int n_in,
                              void* d_out, int out_size, void* d_ws, size_t ws_size,
                              hipStream_t stream) {
  (void)in_sizes; (void)n_in; (void)out_size; (void)ws_size;
  const float* init_noise = (const float*)d_in[0];
  const float* dw_noise   = (const float*)d_in[1];
  const float* emb_W      = (const float*)d_in[3];
  const float* emb_b      = (const float*)d_in[4];
  const float* f_W1       = (const float*)d_in[5];
  const float* f_b1       = (const float*)d_in[6];
  const float* f_W2       = (const float*)d_in[7];
  const float* f_b2       = (const float*)d_in[8];
  const float* f_W3       = (const float*)d_in[9];
  const float* f_b3       = (const float*)d_in[10];
  const float* g_W1       = (const float*)d_in[11];
  const float* g_b1       = (const float*)d_in[12];
  const float* g_W2       = (const float*)d_in[13];
  const float* g_b2       = (const float*)d_in[14];
  const float* g_W3       = (const float*)d_in[15];
  const float* g_b3       = (const float*)d_in[16];
  const float* r_W1       = (const float*)d_in[17];
  const float* r_b1       = (const float*)d_in[18];
  const float* r_W2       = (const float*)d_in[19];
  const float* r_b2       = (const float*)d_in[20];
  float* out_full = (float*)d_out;
  float* out_match = out_full + (size_t)1024 * 512 * 16;

  hipLaunchKernelGGL(prep_kernel, dim3((PREP_TOTAL + 255) / 256), dim3(256), 0, stream,
                     f_W1, g_W1, f_W2, g_W2, f_W3, g_W3, r_W1, r_W2, emb_W, d_ws);
  hipLaunchKernelGGL(sde_main, dim3(512), dim3(512), 0, stream,
                     init_noise, dw_noise, emb_b, f_b1, f_b2, f_b3,
                     g_b1, g_b2, g_b3, r_b1, r_b2, d_ws, out_full, out_match);
}

// Round 7
// 1587.559 us; speedup vs baseline: 4.2654x; 4.2654x over previous
//
#include <hip/hip_runtime.h>
#include <cmath>

// ---------------------------------------------------------------------------
// Round 7: ONE 1024-thread block per CU (16 waves, 4 waves/SIMD) so each SIMD
// has 4 independent streams to hide barrier/latency bubbles, while the single
// block shares ONE copy of the register-resident weights (r6's two-block try
// duplicated work and spilled: VGPR 64 + 16.4GB scratch traffic).
// Weights/wave: L1 tile (8 regs) + L2 tile (16) + L3g 2 tiles (32) = 56 regs.
// rW1 + fW3 live in LDS in fragment-linear layout (lane*16B contiguous ->
// conflict-free ds_read_b128) to keep total live regs ~100 <= 128 cap.
// 4 barriers/step; P4 n-split x2 with shfl_xor(1).
// 256 blocks x 1024 threads x 4 rows.
// ---------------------------------------------------------------------------

typedef _Float16 half8 __attribute__((ext_vector_type(8)));
typedef float floatx4 __attribute__((ext_vector_type(4)));

// ws f16 region (offsets in _Float16 units)
#define H_FW1 0        // [128][64]  col-major-K: k<64 -> fW1[k+1][c]
#define H_GW1 8192     // [128][64]
#define H_FW2 16384    // [128][128]
#define H_GW2 32768    // [128][128]
#define H_GW3 49152    // [512][128]
#define L_RW1 114688   // frag-linear: ((tile*2+kf)*64+lane)*8+j, 8 tiles K=64
#define L_FW3 122880   // frag-linear: ((tile*4+kf)*64+lane)*8+j, 4 tiles K=128
#define H_TOTAL 131072
// f32 region (offsets in float units from ws base)
#define F_BASE 65536
#define F_RW2T (F_BASE + 0)      // [16][132]
#define F_EMBT (F_BASE + 2112)   // [64][32]
#define F_W1R0F (F_BASE + 4160)  // [128]
#define F_W1R0G (F_BASE + 4288)  // [128]
#define F_CNT 4416
#define PREP_TOTAL (H_TOTAL + F_CNT)

__global__ void prep_kernel(const float* __restrict__ fW1, const float* __restrict__ gW1,
                            const float* __restrict__ fW2, const float* __restrict__ gW2,
                            const float* __restrict__ fW3, const float* __restrict__ gW3,
                            const float* __restrict__ rW1, const float* __restrict__ rW2,
                            const float* __restrict__ embW, void* __restrict__ ws) {
  int idx = blockIdx.x * blockDim.x + threadIdx.x;
  if (idx >= PREP_TOTAL) return;
  if (idx < H_TOTAL) {
    float v;
    if (idx < H_GW1) {
      int t = idx; int c = t >> 6, k = t & 63; v = fW1[(k + 1) * 128 + c];
    } else if (idx < H_FW2) {
      int t = idx - H_GW1; int c = t >> 6, k = t & 63; v = gW1[(k + 1) * 128 + c];
    } else if (idx < H_GW2) {
      int t = idx - H_FW2; int c = t >> 7, k = t & 127; v = fW2[k * 128 + c];
    } else if (idx < H_GW3) {
      int t = idx - H_GW2; int c = t >> 7, k = t & 127; v = gW2[k * 128 + c];
    } else if (idx < L_RW1) {
      int t = idx - H_GW3; int c = t >> 7, k = t & 127; v = gW3[k * 512 + c];
    } else if (idx < L_FW3) {
      // rW1 fragment-linear: j, lane, kf(2), tile(8); K=64
      int t = idx - L_RW1;
      int j = t & 7, lane = (t >> 3) & 63, kf = (t >> 9) & 1, tile = t >> 10;
      int n = lane & 15, k = kf * 32 + (lane >> 4) * 8 + j;
      v = rW1[k * 128 + tile * 16 + n];
    } else {
      // fW3 fragment-linear: j, lane, kf(4), tile(4); K=128
      int t = idx - L_FW3;
      int j = t & 7, lane = (t >> 3) & 63, kf = (t >> 9) & 3, tile = t >> 11;
      int n = lane & 15, k = kf * 32 + (lane >> 4) * 8 + j;
      v = fW3[k * 64 + tile * 16 + n];
    }
    ((_Float16*)ws)[idx] = (_Float16)v;
  } else {
    int f = idx - H_TOTAL;
    float v;
    if (f < 2112) {
      int c = f / 132, k = f % 132; v = (k < 128) ? rW2[k * 16 + c] : 0.f;
    } else if (f < 4160) {
      int t = f - 2112; int c = t >> 5, k = t & 31; v = embW[k * 64 + c];
    } else if (f < 4288) {
      v = fW1[f - 4160];     // fW1 row 0 (t-row)
    } else {
      v = gW1[f - 4288];     // gW1 row 0
    }
    ((float*)ws)[F_BASE + f] = v;
  }
}

__device__ __forceinline__ float sp(float x) { return __logf(1.f + __expf(x)); }

__device__ __forceinline__ float ftanh(float x) {
  float cx = fminf(fmaxf(x, -15.f), 15.f);
  float e = __expf(2.f * cx);
  return __fdividef(e - 1.f, e + 1.f);
}

__device__ __forceinline__ floatx4 mfma16(half8 a, half8 b, floatx4 c) {
  return __builtin_amdgcn_mfma_f32_16x16x32_f16(a, b, c, 0, 0, 0);
}

// lane-linear A-layout offset for element (m, k)
__device__ __forceinline__ int aofs(int m, int k) {
  return ((k >> 5) << 9) + (((k >> 3) & 3) << 7) + (m << 3) + (k & 7);
}

__global__ __launch_bounds__(1024)
void sde_main(const float* __restrict__ init_noise, const float* __restrict__ dw_noise,
              const float* __restrict__ emb_b,
              const float* __restrict__ f_b1, const float* __restrict__ f_b2,
              const float* __restrict__ f_b3, const float* __restrict__ g_b1,
              const float* __restrict__ g_b2, const float* __restrict__ g_b3,
              const float* __restrict__ r_b1, const float* __restrict__ r_b2,
              const void* __restrict__ ws, float* __restrict__ out_full,
              float* __restrict__ out_match) {
  // lane-linear f16 activation buffers (rows 4..15 hold garbage; never read)
  __shared__ __align__(16) _Float16 zseg[1024];
  __shared__ __align__(16) _Float16 h1f[2048], h1g[2048];
  __shared__ __align__(16) _Float16 h2f[2048], h2g[2048];
  // LDS-resident weight fragments (frag-linear, conflict-free b128)
  __shared__ __align__(16) _Float16 lds_rw1[8192];   // 8 tiles x 2 kf
  __shared__ __align__(16) _Float16 lds_fw3[8192];   // 4 tiles x 4 kf
  // f32 scratch (4 rows)
  __shared__ __align__(16) float hrs[4 * 132];
  __shared__ __align__(16) float fps[4 * 68];
  __shared__ __align__(16) float gps[4 * 528];
  __shared__ __align__(16) float zb[4 * 68];
  __shared__ __align__(16) float dwS[4][12];
  __shared__ __align__(16) float rw2s[16 * 132];
  __shared__ float b1f[128], b1g[128], b2f[128], b2g[128], fb3[64], gb3[512];
  __shared__ float rb1[128], rb2[16], w1r0f[128], w1r0g[128];

  const int tid = threadIdx.x;
  const int w = tid >> 6;          // wave 0..15
  const int lane = tid & 63;
  const int ln16 = lane & 15;
  const int quad = lane >> 4;
  const int koff = quad * 8;
  const int b4 = blockIdx.x << 2;
  const _Float16* wsh = (const _Float16*)ws;
  const float* wsf = (const float*)ws;

  const float DTI = 1.0f / 511.0f;
  const float SDT = sqrtf(DTI);

  // ---- init ----
  if (tid < 512) gb3[tid] = g_b3[tid];
  if (tid < 128) {
    b1f[tid] = f_b1[tid]; b1g[tid] = g_b1[tid];
    b2f[tid] = f_b2[tid]; b2g[tid] = g_b2[tid];
    rb1[tid] = r_b1[tid];
    w1r0f[tid] = wsf[F_W1R0F + tid]; w1r0g[tid] = wsf[F_W1R0G + tid];
  }
  if (tid < 64) fb3[tid] = f_b3[tid];
  if (tid < 16) rb2[tid] = r_b2[tid];
  for (int o = tid; o < 2112; o += 1024) rw2s[o] = wsf[F_RW2T + o];
  for (int o = tid; o < 4096; o += 1024) {
    ((unsigned int*)lds_rw1)[o] = ((const unsigned int*)(wsh + L_RW1))[o];
    ((unsigned int*)lds_fw3)[o] = ((const unsigned int*)(wsh + L_FW3))[o];
  }
  if (tid < 128) hrs[(tid >> 5) * 132 + (tid & 31)] = init_noise[b4 * 32 + tid];

  // ---- persistent register B-fragments ----
  // waves 0-7: L1 f-tile w ; waves 8-15: L1 g-tile (w-8)
  half8 B1[2];
#pragma unroll
  for (int kf = 0; kf < 2; ++kf) {
    const _Float16* p = (w < 8) ? (wsh + H_FW1 + (w * 16 + ln16) * 64)
                                : (wsh + H_GW1 + ((w - 8) * 16 + ln16) * 64);
    B1[kf] = *(const half8*)(p + kf * 32 + koff);
  }
  // L2: wave w -> tile (w&7) of fW2 (w<8) / gW2 (w>=8)
  half8 B2[4];
  {
    const _Float16* p = wsh + (w < 8 ? H_FW2 : H_GW2) + ((w & 7) * 16 + ln16) * 128;
#pragma unroll
    for (int kf = 0; kf < 4; ++kf) B2[kf] = *(const half8*)(p + kf * 32 + koff);
  }
  // L3g: wave w -> tiles 2w, 2w+1
  half8 B3g[2][4];
#pragma unroll
  for (int i2 = 0; i2 < 2; ++i2)
#pragma unroll
    for (int kf = 0; kf < 4; ++kf)
      B3g[i2][kf] = *(const half8*)(wsh + H_GW3 + ((2 * w + i2) * 16 + ln16) * 128 + kf * 32 + koff);
  __syncthreads();

  // ---- z0 = init_noise @ emb_W + emb_b ----
  if (tid < 256) {
    const int rr = tid & 3, l = tid >> 2;
    const float* pe = wsf + F_EMBT + l * 32;
    float acc = emb_b[l];
#pragma unroll
    for (int c = 0; c < 8; ++c) {
      float4 a = *(const float4*)(&hrs[rr * 132 + 4 * c]);
      float4 v = *(const float4*)(pe + 4 * c);
      acc += a.x * v.x + a.y * v.y + a.z * v.z + a.w * v.w;
    }
    zb[rr * 68 + l] = acc;
    zseg[aofs(rr, l)] = (_Float16)acc;
  }
  __syncthreads();

  // R2 helper: threads [256,512) (waves 4-7)
  auto R2 = [&](int T) {
    const int t2 = tid - 256;
    const int r = t2 & 3, q2 = t2 >> 2, d = q2 >> 2, kk = q2 & 3;
    const float* ph = &hrs[r * 132 + kk * 32];
    const float* pw = &rw2s[d * 132 + kk * 32];
    float acc = 0.f;
#pragma unroll
    for (int c = 0; c < 8; ++c) {
      float4 a4 = *(const float4*)(ph + 4 * c);
      float4 w4 = *(const float4*)(pw + 4 * c);
      acc += a4.x * w4.x + a4.y * w4.y + a4.z * w4.z + a4.w * w4.w;
    }
    acc += __shfl_xor(acc, 4);
    acc += __shfl_xor(acc, 8);
    if (kk == 0) {
      float v = acc + rb2[d];
      out_full[((size_t)(b4 + r) * 512 + T) * 16 + d] = v;
      if ((T & 7) == 0) out_match[((size_t)(b4 + r) * 64 + (T >> 3)) * 16 + d] = v;
    }
  };

#pragma unroll 1
  for (int i = 0; i < 511; ++i) {
    const float t_s = (float)i * DTI;

    // ---- P1: L1 (f on waves 0-7, g+R1 on waves 8-15); dW prefetch ----
    {
      half8 a0 = *(const half8*)(&zseg[lane * 8]);
      half8 a1 = *(const half8*)(&zseg[512 + lane * 8]);
      if (w < 8) {
        floatx4 cf = {0.f, 0.f, 0.f, 0.f};
        cf = mfma16(a0, B1[0], cf); cf = mfma16(a1, B1[1], cf);
        if (quad == 0) {
          int col = w * 16 + ln16;
          float bf = b1f[col] + t_s * w1r0f[col];
          int ho = aofs(0, col);
#pragma unroll
          for (int j = 0; j < 4; ++j) h1f[ho + j * 8] = (_Float16)sp(cf[j] + bf);
        }
      } else {
        // R1 B-frags from LDS (frag-linear, conflict-free)
        half8 br0 = *(const half8*)(&lds_rw1[((w - 8) * 2 + 0) * 512 + lane * 8]);
        half8 br1 = *(const half8*)(&lds_rw1[((w - 8) * 2 + 1) * 512 + lane * 8]);
        floatx4 cg = {0.f, 0.f, 0.f, 0.f}, cr = {0.f, 0.f, 0.f, 0.f};
        cg = mfma16(a0, B1[0], cg); cg = mfma16(a1, B1[1], cg);
        cr = mfma16(a0, br0, cr);   cr = mfma16(a1, br1, cr);
        if (quad == 0) {
          int col = (w - 8) * 16 + ln16;
          float bg = b1g[col] + t_s * w1r0g[col];
          int ho = aofs(0, col);
#pragma unroll
          for (int j = 0; j < 4; ++j) {
            h1g[ho + j * 8] = (_Float16)sp(cg[j] + bg);
            hrs[j * 132 + col] = fmaxf(cr[j] + rb1[col], 0.f);
          }
        }
      }
      if (tid >= 992) {
        int n = tid - 992;   // 32 threads: 4 rows x 8 dims
        dwS[n >> 3][n & 7] = dw_noise[(size_t)i * 8192 + b4 * 8 + n] * SDT;
      }
    }
    __syncthreads();

    // ---- P2: L2 (1 tile/wave) + R2(T=i) on threads [256,512) ----
    {
      const _Float16* asrc = (w < 8) ? h1f : h1g;
      half8 a[4];
#pragma unroll
      for (int s = 0; s < 4; ++s) a[s] = *(const half8*)(&asrc[s * 512 + lane * 8]);
      floatx4 c0 = {0.f, 0.f, 0.f, 0.f};
#pragma unroll
      for (int s = 0; s < 4; ++s) c0 = mfma16(a[s], B2[s], c0);
      if (tid >= 256 && tid < 512) R2(i);
      if (quad == 0) {
        _Float16* dst = (w < 8) ? h2f : h2g;
        const float* bb = (w < 8) ? b2f : b2g;
        int col = (w & 7) * 16 + ln16;
        int ho = aofs(0, col);
#pragma unroll
        for (int j = 0; j < 4; ++j) dst[ho + j * 8] = (_Float16)sp(c0[j] + bb[col]);
      }
    }
    __syncthreads();

    // ---- P3: L3g (2 tiles/wave) + L3f on waves 8-11 (B from LDS) ----
    {
      half8 ag[4];
#pragma unroll
      for (int s = 0; s < 4; ++s) ag[s] = *(const half8*)(&h2g[s * 512 + lane * 8]);
      floatx4 cg0 = {0.f, 0.f, 0.f, 0.f}, cg1 = {0.f, 0.f, 0.f, 0.f};
#pragma unroll
      for (int s = 0; s < 4; ++s) {
        cg0 = mfma16(ag[s], B3g[0][s], cg0);
        cg1 = mfma16(ag[s], B3g[1][s], cg1);
      }
      floatx4 cf3 = {0.f, 0.f, 0.f, 0.f};
      if (w >= 8 && w < 12) {
#pragma unroll
        for (int s = 0; s < 4; ++s) {
          half8 af = *(const half8*)(&h2f[s * 512 + lane * 8]);
          half8 bf = *(const half8*)(&lds_fw3[((w - 8) * 4 + s) * 512 + lane * 8]);
          cf3 = mfma16(af, bf, cf3);
        }
      }
      if (quad == 0) {
        int col0 = (2 * w) * 16 + ln16, col1 = col0 + 16;
#pragma unroll
        for (int j = 0; j < 4; ++j) {
          gps[j * 528 + col0] = cg0[j];
          gps[j * 528 + col1] = cg1[j];
        }
        if (w >= 8 && w < 12) {
          int col = (w - 8) * 16 + ln16;
#pragma unroll
          for (int j = 0; j < 4; ++j) fps[j * 68 + col] = cf3[j];
        }
      }
    }
    __syncthreads();

    // ---- P4: z update, 512 threads, 2-way n-split + shfl_xor(1) ----
    if (tid < 512) {
      const int v = tid >> 1, half = tid & 1;
      const int rr = v & 3, l = v >> 2;
      float acc = 0.f;
      float4 g4 = *(const float4*)(&gps[rr * 528 + l * 8 + half * 4]);
      const float* gb = &gb3[l * 8 + half * 4];
      const float* dw = &dwS[rr][half * 4];
      acc += ftanh(g4.x + gb[0]) * dw[0];
      acc += ftanh(g4.y + gb[1]) * dw[1];
      acc += ftanh(g4.z + gb[2]) * dw[2];
      acc += ftanh(g4.w + gb[3]) * dw[3];
      if (half == 0) acc += ftanh(fps[rr * 68 + l] + fb3[l]) * DTI;
      acc += __shfl_xor(acc, 1);
      if (half == 0) {
        float zn = zb[rr * 68 + l] + acc;
        zb[rr * 68 + l] = zn;
        zseg[aofs(rr, l)] = (_Float16)zn;
      }
    }
    __syncthreads();
  }

  // ---- final readout T=511 ----
  if (w >= 8) {
    half8 a0 = *(const half8*)(&zseg[lane * 8]);
    half8 a1 = *(const half8*)(&zseg[512 + lane * 8]);
    half8 br0 = *(const half8*)(&lds_rw1[((w - 8) * 2 + 0) * 512 + lane * 8]);
    half8 br1 = *(const half8*)(&lds_rw1[((w - 8) * 2 + 1) * 512 + lane * 8]);
    floatx4 cr = {0.f, 0.f, 0.f, 0.f};
    cr = mfma16(a0, br0, cr); cr = mfma16(a1, br1, cr);
    if (quad == 0) {
      int col = (w - 8) * 16 + ln16;
#pragma unroll
      for (int j = 0; j < 4; ++j) hrs[j * 132 + col] = fmaxf(cr[j] + rb1[col], 0.f);
    }
  }
  __syncthreads();
  if (tid >= 256 && tid < 512) R2(511);
}

extern "C" void kernel_launch(void* const* d_in, const int* in_sizes, int n_in,
                              void* d_out, int out_size, void* d_ws, size_t ws_size,
                              hipStream_t stream) {
  (void)in_sizes; (void)n_in; (void)out_size; (void)ws_size;
  const float* init_noise = (const float*)d_in[0];
  const float* dw_noise   = (const float*)d_in[1];
  const float* emb_W      = (const float*)d_in[3];
  const float* emb_b      = (const float*)d_in[4];
  const float* f_W1       = (const float*)d_in[5];
  const float* f_b1       = (const float*)d_in[6];
  const float* f_W2       = (const float*)d_in[7];
  const float* f_b2       = (const float*)d_in[8];
  const float* f_W3       = (const float*)d_in[9];
  const float* f_b3       = (const float*)d_in[10];
  const float* g_W1       = (const float*)d_in[11];
  const float* g_b1       = (const float*)d_in[12];
  const float* g_W2       = (const float*)d_in[13];
  const float* g_b2       = (const float*)d_in[14];
  const float* g_W3       = (const float*)d_in[15];
  const float* g_b3       = (const float*)d_in[16];
  const float* r_W1       = (const float*)d_in[17];
  const float* r_b1       = (const float*)d_in[18];
  const float* r_W2       = (const float*)d_in[19];
  const float* r_b2       = (const float*)d_in[20];
  float* out_full = (float*)d_out;
  float* out_match = out_full + (size_t)1024 * 512 * 16;

  hipLaunchKernelGGL(prep_kernel, dim3((PREP_TOTAL + 255) / 256), dim3(256), 0, stream,
                     f_W1, g_W1, f_W2, g_W2, f_W3, g_W3, r_W1, r_W2, emb_W, d_ws);
  hipLaunchKernelGGL(sde_main, dim3(256), dim3(1024), 0, stream,
                     init_noise, dw_noise, emb_b, f_b1, f_b2, f_b3,
                     g_b1, g_b2, g_b3, r_b1, r_b2, d_ws, out_full, out_match);
}